// Round 2
// baseline (461.433 us; speedup 1.0000x reference)
//
#include <hip/hip_runtime.h>
#include <hip/hip_bf16.h>

#define NN 100000
#define NE 1600000
#define D  128
#define PBLK 256   // partial-reduction blocks for node pass

// K1: deg[v] += edge_attr[e] at dst (self-loop +1 added in K2)
__global__ void k_deg(const int* __restrict__ col, const float* __restrict__ w,
                      float* __restrict__ deg) {
    int e = blockIdx.x * blockDim.x + threadIdx.x;
    if (e < NE) {
        atomicAdd(&deg[col[e]], w[e]);
    }
}

// K2: dinv = rsqrt(deg+1); init c,t with self-loop norm dinv^2.
//     Block 0 additionally computes s1[j] = sum_i W1[i][j]  (ones @ W1).
__global__ void k_dinv(float* __restrict__ deg, float* __restrict__ c, float* __restrict__ t,
                       const float* __restrict__ W1, float* __restrict__ s1) {
    int v = blockIdx.x * blockDim.x + threadIdx.x;
    if (v < NN) {
        float d = deg[v] + 1.0f;               // + self-loop weight 1.0
        float di = d > 0.f ? rsqrtf(d) : 0.f;  // mirrors reference guard
        deg[v] = di;                           // deg array becomes dinv
        float sl = di * di;                    // self-loop norm contribution
        c[v] = sl;
        t[v] = sl;
    }
    if (blockIdx.x == 0 && threadIdx.x < D) {
        int j = threadIdx.x;
        float s = 0.f;
        for (int r = 0; r < D; ++r) s += W1[r * D + j];
        s1[j] = s;
    }
}

// K3: per-edge norm = dinv[row]*w*dinv[col]; scatter into c (by col) and t (by row)
__global__ void k_edge(const int* __restrict__ row, const int* __restrict__ col,
                       const float* __restrict__ w, const float* __restrict__ dinv,
                       float* __restrict__ c, float* __restrict__ t) {
    int e = blockIdx.x * blockDim.x + threadIdx.x;
    if (e < NE) {
        int r = row[e];
        int cc = col[e];
        float n = dinv[r] * w[e] * dinv[cc];
        atomicAdd(&c[cc], n);
        atomicAdd(&t[r], n);
    }
}

// K4: part[b][j] = sum over block-b's slice of nodes of t[v] * relu(c[v]*s1[j] + b1[j])
__global__ void k_node(const float* __restrict__ c, const float* __restrict__ t,
                       const float* __restrict__ s1, const float* __restrict__ b1,
                       float* __restrict__ part) {
    int j = threadIdx.x;              // 0..127
    float s  = s1[j];
    float bb = b1[j];
    float p = 0.f;
    for (int v = blockIdx.x; v < NN; v += gridDim.x) {
        float cv = c[v];              // wave-uniform address -> scalar load
        float tv = t[v];
        float h = fmaf(cv, s, bb);
        p += tv * fmaxf(h, 0.f);
    }
    part[blockIdx.x * D + j] = p;
}

// K5: acc[j] = sum_b part[b][j]; out[k] = (1/N) * sum_j acc[j]*W2[j][k] + b2[k]
__global__ void k_final(const float* __restrict__ part, const float* __restrict__ W2,
                        const float* __restrict__ b2, float* __restrict__ out) {
    __shared__ float accs[D];
    int j = threadIdx.x;              // 0..127
    float a = 0.f;
    for (int b = 0; b < PBLK; ++b) a += part[b * D + j];
    accs[j] = a;
    __syncthreads();
    float o = 0.f;
    for (int jj = 0; jj < D; ++jj) o = fmaf(accs[jj], W2[jj * D + j], o);
    o = o * (1.0f / (float)NN) + b2[j];
    out[j] = o;
}

extern "C" void kernel_launch(void* const* d_in, const int* in_sizes, int n_in,
                              void* d_out, int out_size, void* d_ws, size_t ws_size,
                              hipStream_t stream) {
    // inputs: 0=x [N,128] f32 (unused; reference overwrites with ones),
    //         1=edge_index [2,E] int, 2=edge_attr [E] f32,
    //         3=W1 [128,128] f32, 4=b1 [128] f32, 5=W2 [128,128] f32, 6=b2 [128] f32
    const int* ei  = (const int*)d_in[1];
    const int* row = ei;
    const int* col = ei + NE;
    const float* ea = (const float*)d_in[2];
    const float* W1 = (const float*)d_in[3];
    const float* b1 = (const float*)d_in[4];
    const float* W2 = (const float*)d_in[5];
    const float* b2 = (const float*)d_in[6];
    float* out = (float*)d_out;

    float* ws   = (float*)d_ws;
    float* deg  = ws;                 // [N] -> becomes dinv
    float* c    = ws + NN;            // [N]
    float* t    = ws + 2 * NN;        // [N]
    float* s1   = ws + 3 * NN;        // [128]
    float* part = ws + 3 * NN + D;    // [PBLK*128]

    // d_ws is re-poisoned (0xAA) before every launch: zero only what's accumulated into.
    hipMemsetAsync(deg, 0, NN * sizeof(float), stream);

    k_deg  <<<(NE + 255) / 256, 256, 0, stream>>>(col, ea, deg);
    k_dinv <<<(NN + 255) / 256, 256, 0, stream>>>(deg, c, t, W1, s1);
    k_edge <<<(NE + 255) / 256, 256, 0, stream>>>(row, col, ea, deg, c, t);
    k_node <<<PBLK, D, 0, stream>>>(c, t, s1, b1, part);
    k_final<<<1, D, 0, stream>>>(part, W2, b2, out);
}

// Round 3
// 393.088 us; speedup vs baseline: 1.1739x; 1.1739x over previous
//
#include <hip/hip_runtime.h>
#include <hip/hip_bf16.h>

#define NN 100000
#define NE 1600000
#define D  128
#define BINS 8
#define BINSZ 12500          // BINS*BINSZ == NN; bin = 50 KB LDS
#define GBLK 256             // gather/node partial blocks

// Binned scatter-add: parts[s][v] = sum of val[e] over slice-s edges with key[e]==v-in-bin.
// Grid = BINS * P blocks; block (b,s) owns node range [b*BINSZ, (b+1)*BINSZ) and
// edge slice s. No global atomics: LDS ds_add_f32 + full coalesced flush.
__global__ void k_scatter(const int* __restrict__ key, const float* __restrict__ val,
                          float* __restrict__ parts, int P) {
    __shared__ float bin[BINSZ];
    int b = blockIdx.x % BINS;
    int s = blockIdx.x / BINS;
    for (int i = threadIdx.x; i < BINSZ; i += blockDim.x) bin[i] = 0.f;
    __syncthreads();
    int lo = b * BINSZ;
    int slice = (NE + P - 1) / P;
    int e0 = s * slice;
    int e1 = min(NE, e0 + slice);
    for (int e = e0 + threadIdx.x; e < e1; e += blockDim.x) {
        int rel = key[e] - lo;
        float v = val[e];
        if ((unsigned)rel < (unsigned)BINSZ) atomicAdd(&bin[rel], v);  // ds_add_f32
    }
    __syncthreads();
    float* dst = parts + (size_t)s * NN + lo;
    for (int i = threadIdx.x; i < BINSZ; i += blockDim.x) dst[i] = bin[i];
}

// dinv[v] = rsqrt(1 + sum_s parts[s][v]); block 0 also computes s1[j] = sum_i W1[i][j]
__global__ void k_dinv(const float* __restrict__ parts, int P, const float* __restrict__ W1,
                       float* __restrict__ dinv, float* __restrict__ s1) {
    int v = blockIdx.x * blockDim.x + threadIdx.x;
    if (v < NN) {
        float d = 1.0f;                       // self-loop weight
        for (int s = 0; s < P; ++s) d += parts[(size_t)s * NN + v];
        dinv[v] = rsqrtf(d);                  // d >= 1 always
    }
    if (blockIdx.x == 0 && threadIdx.x < D) {
        int j = threadIdx.x;
        float s = 0.f;
        for (int r = 0; r < D; ++r) s += W1[r * D + j];
        s1[j] = s;
    }
}

// norm[e] = dinv[row]*w*dinv[col]  (gathers happen exactly once)
__global__ void k_norm(const int* __restrict__ row, const int* __restrict__ col,
                       const float* __restrict__ w, const float* __restrict__ dinv,
                       float* __restrict__ norm) {
    int e = blockIdx.x * blockDim.x + threadIdx.x;
    if (e < NE) norm[e] = dinv[row[e]] * w[e] * dinv[col[e]];
}

// c[v] = sum_s parts[s][v] + dinv[v]^2   (self-loop norm)
__global__ void k_cred(const float* __restrict__ parts, int P, const float* __restrict__ dinv,
                       float* __restrict__ c) {
    int v = blockIdx.x * blockDim.x + threadIdx.x;
    if (v < NN) {
        float dv = dinv[v];
        float a = dv * dv;
        for (int s = 0; s < P; ++s) a += parts[(size_t)s * NN + v];
        c[v] = a;
    }
}

// Edge-gather replaces the t-scatter: gpart[blk][j] = sum over blk's edges of
//   norm_e * relu(c[row_e]*s1[j] + b1[j])
// Block = 256 thr = two 128-lane j-groups; edges staged through LDS.
__global__ void k_gather(const int* __restrict__ row, const float* __restrict__ norm,
                         const float* __restrict__ c, const float* __restrict__ s1,
                         const float* __restrict__ b1, float* __restrict__ gpart) {
    __shared__ float s_n[256], s_c[256], red[D];
    int j = threadIdx.x & (D - 1);
    int g = threadIdx.x >> 7;
    float s  = s1[j];
    float bb = b1[j];
    float acc = 0.f;
    for (int base = blockIdx.x * 256; base < NE; base += gridDim.x * 256) {
        int e = base + threadIdx.x;
        float nv = 0.f, cv = 0.f;
        if (e < NE) { nv = norm[e]; cv = c[row[e]]; }
        __syncthreads();                       // previous batch fully consumed
        s_n[threadIdx.x] = nv;
        s_c[threadIdx.x] = cv;
        __syncthreads();
        int off = g * 128;
        #pragma unroll 8
        for (int q = 0; q < 128; ++q) {
            float n  = s_n[off + q];           // LDS broadcast
            float cc = s_c[off + q];
            acc += n * fmaxf(fmaf(cc, s, bb), 0.f);
        }
    }
    if (g) red[j] = acc;
    __syncthreads();
    if (!g) gpart[blockIdx.x * D + j] = acc + red[j];
}

// Node self-loop term: npart[blk][j] = sum over blk's nodes of dinv^2 * relu(c*s1+b1)
__global__ void k_node(const float* __restrict__ dinv, const float* __restrict__ c,
                       const float* __restrict__ s1, const float* __restrict__ b1,
                       float* __restrict__ npart) {
    __shared__ float red[D];
    int j = threadIdx.x & (D - 1);
    int g = threadIdx.x >> 7;
    float s  = s1[j];
    float bb = b1[j];
    float acc = 0.f;
    for (int v = blockIdx.x * 2 + g; v < NN; v += gridDim.x * 2) {
        float dv = dinv[v];                    // broadcast load (L2-resident)
        float cv = c[v];
        acc += dv * dv * fmaxf(fmaf(cv, s, bb), 0.f);
    }
    if (g) red[j] = acc;
    __syncthreads();
    if (!g) npart[blockIdx.x * D + j] = acc + red[j];
}

// acc[j] = sum_r gpart[r][j]+npart[r][j];  out[k] = (1/N)*sum_j acc[j]*W2[j][k] + b2[k]
__global__ void k_final(const float* __restrict__ gpart, const float* __restrict__ npart,
                        const float* __restrict__ W2, const float* __restrict__ b2,
                        float* __restrict__ out) {
    __shared__ float accs[D], red[D], red2[D];
    int j = threadIdx.x & (D - 1);
    int g = threadIdx.x >> 7;
    float a = 0.f;
    for (int r = g; r < GBLK; r += 2) a += gpart[r * D + j] + npart[r * D + j];
    if (g) red[j] = a;
    __syncthreads();
    if (!g) accs[j] = a + red[j];
    __syncthreads();
    float o = 0.f;
    int jj0 = g * 64;
    #pragma unroll 8
    for (int jj = jj0; jj < jj0 + 64; ++jj) o = fmaf(accs[jj], W2[jj * D + j], o);
    if (g) red2[j] = o;
    __syncthreads();
    if (!g) out[j] = (o + red2[j]) * (1.0f / (float)NN) + b2[j];
}

extern "C" void kernel_launch(void* const* d_in, const int* in_sizes, int n_in,
                              void* d_out, int out_size, void* d_ws, size_t ws_size,
                              hipStream_t stream) {
    // inputs: 0=x (unused; ref overwrites with ones), 1=edge_index [2,E] int,
    //         2=edge_attr [E] f32, 3=W1, 4=b1, 5=W2, 6=b2 (all f32)
    const int* ei  = (const int*)d_in[1];
    const int* row = ei;
    const int* col = ei + NE;
    const float* ea = (const float*)d_in[2];
    const float* W1 = (const float*)d_in[3];
    const float* b1 = (const float*)d_in[4];
    const float* W2 = (const float*)d_in[5];
    const float* b2 = (const float*)d_in[6];
    float* out = (float*)d_out;

    // Pick slice count P to fit ws (deterministic across calls: depends only on ws_size)
    int P = 32;
    while (P > 4) {
        size_t need = ((size_t)P * NN + 2 * NN + D + NE + 2 * GBLK * D) * sizeof(float);
        if (need <= ws_size) break;
        P >>= 1;
    }

    float* ws    = (float*)d_ws;
    float* parts = ws;                          // [P*NN]  (reused: deg pass then c pass)
    float* dinv  = parts + (size_t)P * NN;      // [NN]
    float* c     = dinv + NN;                   // [NN]
    float* s1    = c + NN;                      // [D]
    float* norm  = s1 + D;                      // [NE]
    float* gpart = norm + NE;                   // [GBLK*D]
    float* npart = gpart + GBLK * D;            // [GBLK*D]

    // No memset needed: every ws region is fully written before it is read.
    k_scatter<<<BINS * P, 512, 0, stream>>>(col, ea, parts, P);          // deg partials
    k_dinv   <<<(NN + 255) / 256, 256, 0, stream>>>(parts, P, W1, dinv, s1);
    k_norm   <<<(NE + 255) / 256, 256, 0, stream>>>(row, col, ea, dinv, norm);
    k_scatter<<<BINS * P, 512, 0, stream>>>(col, norm, parts, P);        // c partials
    k_cred   <<<(NN + 255) / 256, 256, 0, stream>>>(parts, P, dinv, c);
    k_gather <<<GBLK, 256, 0, stream>>>(row, norm, c, s1, b1, gpart);
    k_node   <<<GBLK, 256, 0, stream>>>(dinv, c, s1, b1, npart);
    k_final  <<<1, 256, 0, stream>>>(gpart, npart, W2, b2, out);
}

// Round 4
// 254.969 us; speedup vs baseline: 1.8098x; 1.5417x over previous
//
#include <hip/hip_runtime.h>
#include <hip/hip_bf16.h>

#define NN 100000
#define NE 1600000
#define D  128
#define BINS 8
#define BINSZ 12500          // BINS*BINSZ == NN; bin = 50 KB LDS -> 3 blocks/CU max
#define GB 512               // gather grid
#define GT 512               // gather block

// Binned scatter-add, 4 edges/thread vector loads.
// Block (b = blk%BINS, s = blk/BINS): node range [b*BINSZ,(b+1)*BINSZ), edge slice s of P.
// parts[s][v] partial sums; no global atomics (LDS ds_add + coalesced float4 flush).
__global__ __launch_bounds__(512) void k_scat(const int4* __restrict__ key4,
                                              const float4* __restrict__ val4,
                                              float* __restrict__ parts, int P) {
    __shared__ float bin[BINSZ];
    int b = blockIdx.x % BINS;
    int s = blockIdx.x / BINS;
    float4* bin4 = (float4*)bin;
    for (int i = threadIdx.x; i < BINSZ / 4; i += blockDim.x)
        bin4[i] = make_float4(0.f, 0.f, 0.f, 0.f);
    __syncthreads();
    int lo = b * BINSZ;
    int slice4 = NE / 4 / P;           // exact: NE divisible by 4P for P in {4..64}
    int e0 = s * slice4, e1 = e0 + slice4;
    for (int e = e0 + threadIdx.x; e < e1; e += blockDim.x) {
        int4 k = key4[e];
        float4 v = val4[e];
        int r0 = k.x - lo, r1 = k.y - lo, r2 = k.z - lo, r3 = k.w - lo;
        if ((unsigned)r0 < (unsigned)BINSZ) atomicAdd(&bin[r0], v.x);
        if ((unsigned)r1 < (unsigned)BINSZ) atomicAdd(&bin[r1], v.y);
        if ((unsigned)r2 < (unsigned)BINSZ) atomicAdd(&bin[r2], v.z);
        if ((unsigned)r3 < (unsigned)BINSZ) atomicAdd(&bin[r3], v.w);
    }
    __syncthreads();
    float4* dst4 = (float4*)(parts + (size_t)s * NN + lo);
    for (int i = threadIdx.x; i < BINSZ / 4; i += blockDim.x) dst4[i] = bin4[i];
}

// dinv[v] = rsqrt(1 + sum_s parts[s][v]); block 0 also: s1[j] = sum_i W1[i][j]
template <int P>
__global__ void k_red1(const float* __restrict__ parts, const float* __restrict__ W1,
                       float* __restrict__ dinv, float* __restrict__ s1) {
    int v4 = blockIdx.x * blockDim.x + threadIdx.x;
    if (v4 < NN / 4) {
        float4 a = make_float4(1.f, 1.f, 1.f, 1.f);   // self-loop weight
        #pragma unroll
        for (int s = 0; s < P; ++s) {
            float4 p = ((const float4*)(parts + (size_t)s * NN))[v4];
            a.x += p.x; a.y += p.y; a.z += p.z; a.w += p.w;
        }
        float4 r;
        r.x = rsqrtf(a.x); r.y = rsqrtf(a.y); r.z = rsqrtf(a.z); r.w = rsqrtf(a.w);
        ((float4*)dinv)[v4] = r;
    }
    if (blockIdx.x == 0 && threadIdx.x < D) {
        int j = threadIdx.x;
        float s = 0.f;
        for (int r = 0; r < D; ++r) s += W1[r * D + j];
        s1[j] = s;
    }
}

// val2[e] = w[e] * dinv[row[e]]   (the only place dinv[row] is gathered for the scatter)
__global__ void k_val2(const int4* __restrict__ row4, const float4* __restrict__ w4,
                       const float* __restrict__ dinv, float4* __restrict__ out4) {
    int e4 = blockIdx.x * blockDim.x + threadIdx.x;
    if (e4 < NE / 4) {
        int4 r = row4[e4];
        float4 w = w4[e4];
        float4 o;
        o.x = w.x * dinv[r.x]; o.y = w.y * dinv[r.y];
        o.z = w.z * dinv[r.z]; o.w = w.w * dinv[r.w];
        out4[e4] = o;
    }
}

// c[v] = dinv[v]*(S[v] + dinv[v])  where S = sum_s parts  (== dinv*S + dinv^2)
template <int P>
__global__ void k_red2(const float* __restrict__ parts, const float* __restrict__ dinv,
                       float* __restrict__ c) {
    int v4 = blockIdx.x * blockDim.x + threadIdx.x;
    if (v4 < NN / 4) {
        float4 a = make_float4(0.f, 0.f, 0.f, 0.f);
        #pragma unroll
        for (int s = 0; s < P; ++s) {
            float4 p = ((const float4*)(parts + (size_t)s * NN))[v4];
            a.x += p.x; a.y += p.y; a.z += p.z; a.w += p.w;
        }
        float4 dv = ((const float4*)dinv)[v4];
        float4 r;
        r.x = dv.x * (a.x + dv.x); r.y = dv.y * (a.y + dv.y);
        r.z = dv.z * (a.z + dv.z); r.w = dv.w * (a.w + dv.w);
        ((float4*)c)[v4] = r;
    }
}

// gpart[blk][j] = sum over blk's edges of norm_e*relu(c[row_e]*s1[j]+b1[j])
//              + sum over blk's nodes of dinv[v]^2*relu(c[v]*s1[j]+b1[j])
// norm computed on the fly (dinv/c are L2-resident, 800 KB total).
// 512 thr = 4 j-groups of 128; group g consumes staged edges [g*128,(g+1)*128).
__global__ __launch_bounds__(512) void k_gath(const int* __restrict__ row,
                                              const int* __restrict__ col,
                                              const float* __restrict__ w,
                                              const float* __restrict__ dinv,
                                              const float* __restrict__ c,
                                              const float* __restrict__ s1,
                                              const float* __restrict__ b1,
                                              float* __restrict__ gpart) {
    __shared__ float s_n[GT], s_c[GT], red[3 * D];
    int tid = threadIdx.x;
    int j = tid & (D - 1);
    int g = tid >> 7;
    float s  = s1[j];
    float bb = b1[j];
    float acc = 0.f;
    for (int base = blockIdx.x * GT; base < NE; base += gridDim.x * GT) {
        int e = base + tid;
        float nv = 0.f, cv = 0.f;
        if (e < NE) {
            int r = row[e], cc = col[e];
            nv = dinv[r] * w[e] * dinv[cc];
            cv = c[r];
        }
        __syncthreads();                 // previous batch fully consumed
        s_n[tid] = nv;
        s_c[tid] = cv;
        __syncthreads();
        int off = g * 128;
        #pragma unroll 16
        for (int q = 0; q < 128; ++q) {
            float n  = s_n[off + q];     // broadcast within group
            float cc2 = s_c[off + q];
            acc += n * fmaxf(fmaf(cc2, s, bb), 0.f);
        }
    }
    // self-loop (node) term
    for (int v = blockIdx.x * 4 + g; v < NN; v += gridDim.x * 4) {
        float dv = dinv[v];
        float cv = c[v];
        acc += dv * dv * fmaxf(fmaf(cv, s, bb), 0.f);
    }
    if (g) red[(g - 1) * D + j] = acc;
    __syncthreads();
    if (!g) gpart[blockIdx.x * D + j] = acc + red[j] + red[D + j] + red[2 * D + j];
}

// acc[j] = sum_r gpart[r][j];  out[k] = (1/N)*sum_j acc[j]*W2[j][k] + b2[k]
__global__ void k_final(const float* __restrict__ gpart, const float* __restrict__ W2,
                        const float* __restrict__ b2, float* __restrict__ out) {
    __shared__ float accs[D], red[D], red2[D];
    int j = threadIdx.x & (D - 1);
    int g = threadIdx.x >> 7;            // 0..1
    float a = 0.f;
    for (int r = g; r < GB; r += 2) a += gpart[r * D + j];
    if (g) red[j] = a;
    __syncthreads();
    if (!g) accs[j] = a + red[j];
    __syncthreads();
    float o = 0.f;
    int jj0 = g * 64;
    #pragma unroll 16
    for (int jj = jj0; jj < jj0 + 64; ++jj) o = fmaf(accs[jj], W2[jj * D + j], o);
    if (g) red2[j] = o;
    __syncthreads();
    if (!g) out[j] = (o + red2[j]) * (1.0f / (float)NN) + b2[j];
}

template <int P>
static void launch_reds(int which, const float* parts, const float* W1, float* dinv,
                        float* s1, float* c, hipStream_t stream) {
    int blocks = (NN / 4 + 255) / 256;
    if (which == 1) k_red1<P><<<blocks, 256, 0, stream>>>(parts, W1, dinv, s1);
    else            k_red2<P><<<blocks, 256, 0, stream>>>(parts, dinv, c);
}

extern "C" void kernel_launch(void* const* d_in, const int* in_sizes, int n_in,
                              void* d_out, int out_size, void* d_ws, size_t ws_size,
                              hipStream_t stream) {
    // inputs: 0=x (unused; ref overwrites with ones), 1=edge_index [2,E] int,
    //         2=edge_attr [E] f32, 3=W1, 4=b1, 5=W2, 6=b2 (all f32)
    const int* ei  = (const int*)d_in[1];
    const int* row = ei;
    const int* col = ei + NE;
    const float* ea = (const float*)d_in[2];
    const float* W1 = (const float*)d_in[3];
    const float* b1 = (const float*)d_in[4];
    const float* W2 = (const float*)d_in[5];
    const float* b2 = (const float*)d_in[6];
    float* out = (float*)d_out;

    // Slice count P (deterministic: depends only on ws_size)
    int P = 64;
    while (P > 4) {
        size_t need = ((size_t)P * NN + 2 * NN + D + NE + (size_t)GB * D) * sizeof(float);
        if (need <= ws_size) break;
        P >>= 1;
    }

    float* ws    = (float*)d_ws;
    float* parts = ws;                          // [P*NN]   (deg pass, then S pass)
    float* dinv  = parts + (size_t)P * NN;      // [NN]
    float* c     = dinv + NN;                   // [NN]
    float* s1    = c + NN;                      // [D]
    float* val2  = s1 + D;                      // [NE]
    float* gpart = val2 + NE;                   // [GB*D]

    // Every ws region is fully written before read -> no memset.
    k_scat <<<BINS * P, 512, 0, stream>>>((const int4*)col, (const float4*)ea, parts, P);
    switch (P) {   // templated reduce #1 (dinv + s1)
        case 64: launch_reds<64>(1, parts, W1, dinv, s1, c, stream); break;
        case 32: launch_reds<32>(1, parts, W1, dinv, s1, c, stream); break;
        case 16: launch_reds<16>(1, parts, W1, dinv, s1, c, stream); break;
        case 8:  launch_reds<8> (1, parts, W1, dinv, s1, c, stream); break;
        default: launch_reds<4> (1, parts, W1, dinv, s1, c, stream); break;
    }
    k_val2 <<<(NE / 4 + 255) / 256, 256, 0, stream>>>((const int4*)row, (const float4*)ea,
                                                      dinv, (float4*)val2);
    k_scat <<<BINS * P, 512, 0, stream>>>((const int4*)col, (const float4*)val2, parts, P);
    switch (P) {   // templated reduce #2 (c)
        case 64: launch_reds<64>(2, parts, W1, dinv, s1, c, stream); break;
        case 32: launch_reds<32>(2, parts, W1, dinv, s1, c, stream); break;
        case 16: launch_reds<16>(2, parts, W1, dinv, s1, c, stream); break;
        case 8:  launch_reds<8> (2, parts, W1, dinv, s1, c, stream); break;
        default: launch_reds<4> (2, parts, W1, dinv, s1, c, stream); break;
    }
    k_gath <<<GB, GT, 0, stream>>>(row, col, ea, dinv, c, s1, b1, gpart);
    k_final<<<1, 256, 0, stream>>>(gpart, W2, b2, out);
}

// Round 5
// 169.067 us; speedup vs baseline: 2.7293x; 1.5081x over previous
//
#include <hip/hip_runtime.h>
#include <hip/hip_bf16.h>

#define NN   100000
#define NE   1600000
#define D    128
#define BINS 16
#define BSZ  6256               // bin node range (floats); BINS*BSZ = 100096 >= NN
#define NNP  (BINS * BSZ)       // padded per-slice stride (float4-aligned bins)
#define NB   391                // k_node blocks: 391*256 >= NN

// XCD-swizzled (bin,slice) from blockIdx: co-slice bins land on one XCD, adjacent in time.
__device__ __forceinline__ void bin_slice(int blk, int P, int& b, int& s) {
    int x = blk & 7, y = blk >> 3;      // y in [0, 2P)
    s = x * (P >> 3) + (y >> 4);        // (y>>4) in [0, P/8)
    b = y & 15;
}

// ---- scatter 1: deg partials (key=col, val=edge_attr) ----
__global__ __launch_bounds__(1024) void k_scat1(const int4* __restrict__ col4,
                                                const float4* __restrict__ w4,
                                                float* __restrict__ parts, int P) {
    __shared__ float bin[BSZ];
    int b, s; bin_slice(blockIdx.x, P, b, s);
    float4* bin4 = (float4*)bin;
    for (int i = threadIdx.x; i < BSZ / 4; i += blockDim.x) bin4[i] = make_float4(0, 0, 0, 0);
    __syncthreads();
    int lo = b * BSZ;
    int sl4 = NE / 4 / P;
    int e1 = (s + 1) * sl4;
    for (int e = s * sl4 + threadIdx.x; e < e1; e += blockDim.x) {
        int4 k = col4[e]; float4 v = w4[e];
        int r0 = k.x - lo, r1 = k.y - lo, r2 = k.z - lo, r3 = k.w - lo;
        if ((unsigned)r0 < (unsigned)BSZ) atomicAdd(&bin[r0], v.x);
        if ((unsigned)r1 < (unsigned)BSZ) atomicAdd(&bin[r1], v.y);
        if ((unsigned)r2 < (unsigned)BSZ) atomicAdd(&bin[r2], v.z);
        if ((unsigned)r3 < (unsigned)BSZ) atomicAdd(&bin[r3], v.w);
    }
    __syncthreads();
    float4* dst = (float4*)(parts + (size_t)s * NNP + lo);
    for (int i = threadIdx.x; i < BSZ / 4; i += blockDim.x) dst[i] = bin4[i];
}

// dinv[v] = rsqrt(1 + sum_s partsA[s][v]); block 0: s1[j] = sum_i W1[i][j], acc_g = 0
template <int P>
__global__ void k_red1(const float* __restrict__ parts, const float* __restrict__ W1,
                       float* __restrict__ dinv, float* __restrict__ s1,
                       float* __restrict__ acc_g) {
    int v4 = blockIdx.x * blockDim.x + threadIdx.x;
    if (v4 < NN / 4) {
        float4 a = make_float4(1.f, 1.f, 1.f, 1.f);   // self-loop weight
        #pragma unroll
        for (int s = 0; s < P; ++s) {
            float4 p = ((const float4*)(parts + (size_t)s * NNP))[v4];
            a.x += p.x; a.y += p.y; a.z += p.z; a.w += p.w;
        }
        float4 r;
        r.x = rsqrtf(a.x); r.y = rsqrtf(a.y); r.z = rsqrtf(a.z); r.w = rsqrtf(a.w);
        ((float4*)dinv)[v4] = r;
    }
    if (blockIdx.x == 0 && threadIdx.x < D) {
        int j = threadIdx.x;
        float s = 0.f;
        for (int r = 0; r < D; ++r) s += W1[r * D + j];
        s1[j] = s;
        acc_g[j] = 0.f;                               // ws is re-poisoned each call
    }
}

// ---- scatter 2 (fused): S[v]=sum_{col=v} w*dinv[row]  and  U[v]=sum_{row=v} w*dinv[col]
// One edge pass, two LDS bins; dinv gathers gated on bin match (2*NE total gathers).
__global__ __launch_bounds__(1024) void k_scat2(const int4* __restrict__ col4,
                                                const int4* __restrict__ row4,
                                                const float4* __restrict__ w4,
                                                const float* __restrict__ dinv,
                                                float* __restrict__ pS,
                                                float* __restrict__ pU, int P) {
    __shared__ float binS[BSZ];
    __shared__ float binU[BSZ];
    int b, s; bin_slice(blockIdx.x, P, b, s);
    float4* bS4 = (float4*)binS;
    float4* bU4 = (float4*)binU;
    for (int i = threadIdx.x; i < BSZ / 4; i += blockDim.x) {
        bS4[i] = make_float4(0, 0, 0, 0);
        bU4[i] = make_float4(0, 0, 0, 0);
    }
    __syncthreads();
    int lo = b * BSZ;
    int sl4 = NE / 4 / P;
    int e1 = (s + 1) * sl4;
    for (int e = s * sl4 + threadIdx.x; e < e1; e += blockDim.x) {
        int4 kc = col4[e]; int4 kr = row4[e]; float4 w = w4[e];
        int c0 = kc.x - lo, c1 = kc.y - lo, c2 = kc.z - lo, c3 = kc.w - lo;
        int r0 = kr.x - lo, r1 = kr.y - lo, r2 = kr.z - lo, r3 = kr.w - lo;
        if ((unsigned)c0 < (unsigned)BSZ) atomicAdd(&binS[c0], w.x * dinv[kr.x]);
        if ((unsigned)c1 < (unsigned)BSZ) atomicAdd(&binS[c1], w.y * dinv[kr.y]);
        if ((unsigned)c2 < (unsigned)BSZ) atomicAdd(&binS[c2], w.z * dinv[kr.z]);
        if ((unsigned)c3 < (unsigned)BSZ) atomicAdd(&binS[c3], w.w * dinv[kr.w]);
        if ((unsigned)r0 < (unsigned)BSZ) atomicAdd(&binU[r0], w.x * dinv[kc.x]);
        if ((unsigned)r1 < (unsigned)BSZ) atomicAdd(&binU[r1], w.y * dinv[kc.y]);
        if ((unsigned)r2 < (unsigned)BSZ) atomicAdd(&binU[r2], w.z * dinv[kc.z]);
        if ((unsigned)r3 < (unsigned)BSZ) atomicAdd(&binU[r3], w.w * dinv[kc.w]);
    }
    __syncthreads();
    float4* dS = (float4*)(pS + (size_t)s * NNP + lo);
    float4* dU = (float4*)(pU + (size_t)s * NNP + lo);
    for (int i = threadIdx.x; i < BSZ / 4; i += blockDim.x) { dS[i] = bS4[i]; dU[i] = bU4[i]; }
}

// c[v] = dinv*(S+dinv)   (layer-1 aggregate coefficient, incl. self-loop)
// wgt[v] = dinv*(U+dinv) (node weight for the collapsed layer-2+mean sum)
template <int P>
__global__ void k_red2(const float* __restrict__ pS, const float* __restrict__ pU,
                       const float* __restrict__ dinv, float* __restrict__ c,
                       float* __restrict__ wgt) {
    int v4 = blockIdx.x * blockDim.x + threadIdx.x;
    if (v4 >= NN / 4) return;
    float4 S = make_float4(0, 0, 0, 0), U = make_float4(0, 0, 0, 0);
    #pragma unroll
    for (int s = 0; s < P; ++s) {
        float4 a = ((const float4*)(pS + (size_t)s * NNP))[v4];
        float4 b = ((const float4*)(pU + (size_t)s * NNP))[v4];
        S.x += a.x; S.y += a.y; S.z += a.z; S.w += a.w;
        U.x += b.x; U.y += b.y; U.z += b.z; U.w += b.w;
    }
    float4 dv = ((const float4*)dinv)[v4];
    float4 cc, ww;
    cc.x = dv.x * (S.x + dv.x); cc.y = dv.y * (S.y + dv.y);
    cc.z = dv.z * (S.z + dv.z); cc.w = dv.w * (S.w + dv.w);
    ww.x = dv.x * (U.x + dv.x); ww.y = dv.y * (U.y + dv.y);
    ww.z = dv.z * (U.z + dv.z); ww.w = dv.w * (U.w + dv.w);
    ((float4*)c)[v4] = cc;
    ((float4*)wgt)[v4] = ww;
}

// acc_g[j] += sum over this block's 256 nodes of wgt_v * relu(c_v*s1[j] + b1[j])
__global__ __launch_bounds__(256) void k_node(const float* __restrict__ wgt,
                                              const float* __restrict__ c,
                                              const float* __restrict__ s1,
                                              const float* __restrict__ b1,
                                              float* __restrict__ acc_g) {
    __shared__ float4 sw4[64], sc4[64];
    __shared__ float red[D];
    int tid = threadIdx.x;
    int j = tid & (D - 1);
    int g = tid >> 7;
    int v = blockIdx.x * 256 + tid;
    float wv = 0.f, cv = 0.f;
    if (v < NN) { wv = wgt[v]; cv = c[v]; }
    ((float*)sw4)[tid] = wv;
    ((float*)sc4)[tid] = cv;
    __syncthreads();
    float sj = s1[j], bj = b1[j];
    float acc = 0.f;
    int q0 = g * 32;
    #pragma unroll
    for (int q = 0; q < 32; ++q) {
        float4 w4 = sw4[q0 + q];               // wave-uniform LDS broadcast
        float4 c4 = sc4[q0 + q];
        acc += w4.x * fmaxf(fmaf(c4.x, sj, bj), 0.f);
        acc += w4.y * fmaxf(fmaf(c4.y, sj, bj), 0.f);
        acc += w4.z * fmaxf(fmaf(c4.z, sj, bj), 0.f);
        acc += w4.w * fmaxf(fmaf(c4.w, sj, bj), 0.f);
    }
    if (g) red[j] = acc;
    __syncthreads();
    if (!g) atomicAdd(&acc_g[j], acc + red[j]);
}

// out[k] = (1/N) * sum_j acc_g[j]*W2[j][k] + b2[k]
__global__ __launch_bounds__(256) void k_gemv(const float* __restrict__ acc_g,
                                              const float* __restrict__ W2,
                                              const float* __restrict__ b2,
                                              float* __restrict__ out) {
    __shared__ float a[D], r2[D];
    int tid = threadIdx.x, k = tid & (D - 1), g = tid >> 7;
    if (tid < D) a[tid] = acc_g[tid];
    __syncthreads();
    float o = 0.f;
    int j0 = g * 64;
    #pragma unroll 16
    for (int j = j0; j < j0 + 64; ++j) o = fmaf(a[j], W2[j * D + k], o);
    if (g) r2[k] = o;
    __syncthreads();
    if (!g) out[k] = (o + r2[k]) * (1.0f / (float)NN) + b2[k];
}

template <int P>
static void launch_all(const int* row, const int* col, const float* ea, const float* W1,
                       const float* b1, const float* W2, const float* b2, float* out,
                       float* ws, hipStream_t stream) {
    float* pA    = ws;                              // [P*NNP]  deg partials, then S
    float* pB    = pA + (size_t)P * NNP;            // [P*NNP]  U partials
    float* dinv  = pB + (size_t)P * NNP;            // [NN]
    float* c     = dinv + NN;                       // [NN]
    float* wgt   = c + NN;                          // [NN]
    float* s1    = wgt + NN;                        // [D]
    float* acc_g = s1 + D;                          // [D]

    int rb = (NN / 4 + 255) / 256;
    k_scat1<<<BINS * P, 1024, 0, stream>>>((const int4*)col, (const float4*)ea, pA, P);
    k_red1<P><<<rb, 256, 0, stream>>>(pA, W1, dinv, s1, acc_g);
    k_scat2<<<BINS * P, 1024, 0, stream>>>((const int4*)col, (const int4*)row,
                                           (const float4*)ea, dinv, pA, pB, P);
    k_red2<P><<<rb, 256, 0, stream>>>(pA, pB, dinv, c, wgt);
    k_node<<<NB, 256, 0, stream>>>(wgt, c, s1, b1, acc_g);
    k_gemv<<<1, 256, 0, stream>>>(acc_g, W2, b2, out);
}

extern "C" void kernel_launch(void* const* d_in, const int* in_sizes, int n_in,
                              void* d_out, int out_size, void* d_ws, size_t ws_size,
                              hipStream_t stream) {
    // inputs: 0=x (unused; ref overwrites with ones), 1=edge_index [2,E] int,
    //         2=edge_attr [E] f32, 3=W1, 4=b1, 5=W2, 6=b2 (all f32)
    const int* ei  = (const int*)d_in[1];
    const int* row = ei;
    const int* col = ei + NE;
    const float* ea = (const float*)d_in[2];
    const float* W1 = (const float*)d_in[3];
    const float* b1 = (const float*)d_in[4];
    const float* W2 = (const float*)d_in[5];
    const float* b2 = (const float*)d_in[6];
    float* out = (float*)d_out;
    float* ws  = (float*)d_ws;

    // Slice count P (deterministic: depends only on ws_size). ws need = 2*P*NNP + 3*NN + 2*D.
    size_t fixed = 3 * (size_t)NN + 2 * D;
    if (((size_t)2 * 32 * NNP + fixed) * sizeof(float) <= ws_size)
        launch_all<32>(row, col, ea, W1, b1, W2, b2, out, ws, stream);
    else if (((size_t)2 * 16 * NNP + fixed) * sizeof(float) <= ws_size)
        launch_all<16>(row, col, ea, W1, b1, W2, b2, out, ws, stream);
    else
        launch_all<8>(row, col, ea, W1, b1, W2, b2, out, ws, stream);
}